// Round 2
// baseline (937.973 us; speedup 1.0000x reference)
//
#include <hip/hip_runtime.h>
#include <cstddef>

#define B_  8
#define C_  512
#define N_  16384
#define IC_ 64
#define NSPLIT_ 64                 // score-reduction splits per batch
#define CHUNKS_ (N_ / (NSPLIT_ * 64))   // n-chunks of 64 per split = 4

// 4x4 outer-product accumulate from two float4s into named acc array
#define FMA16(A, av, bv)                                                \
  A[0][0] += (av).x*(bv).x; A[0][1] += (av).x*(bv).y;                   \
  A[0][2] += (av).x*(bv).z; A[0][3] += (av).x*(bv).w;                   \
  A[1][0] += (av).y*(bv).x; A[1][1] += (av).y*(bv).y;                   \
  A[1][2] += (av).y*(bv).z; A[1][3] += (av).y*(bv).w;                   \
  A[2][0] += (av).z*(bv).x; A[2][1] += (av).z*(bv).y;                   \
  A[2][2] += (av).z*(bv).z; A[2][3] += (av).z*(bv).w;                   \
  A[3][0] += (av).w*(bv).x; A[3][1] += (av).w*(bv).y;                   \
  A[3][2] += (av).w*(bv).z; A[3][3] += (av).w*(bv).w;

// ---------------------------------------------------------------------------
// Kernel 1: fused Q,K projection + scores partial accumulation.
// Per block: one (b, nsplit). For each 64-wide n-chunk: compute Q,K tiles
// [64ic x 64n] in registers from x (shared x-tile LDS reads serve both),
// round-trip through LDS to transpose, accumulate S[b,i,j] += Q·K^T,
// atomicAdd into global S at the end.
// Q and K never touch HBM.
// ---------------------------------------------------------------------------
__global__ __launch_bounds__(256) void qk_scores_kernel(
    const float* __restrict__ x,
    const float* __restrict__ Wq, const float* __restrict__ bq,
    const float* __restrict__ Wk, const float* __restrict__ bk,
    float* __restrict__ S)
{
    const int bid    = blockIdx.x;
    const int nsplit = bid % NSPLIT_;
    const int b      = bid / NSPLIT_;

    __shared__ float Wqt[64][68];  // [cc][ic] staging; reused as Qlds[nn][i]
    __shared__ float Wkt[64][68];  // [cc][ic] staging; reused as Klds[nn][j]
    __shared__ float Xt [64][68];  // [cc][nn]

    const int tid = threadIdx.x;
    const int tx  = tid & 15;      // n-quad (later j-quad)
    const int ty  = tid >> 4;      // ic-quad (later i-quad)

    float sacc[4][4] = {};

    for (int ch = 0; ch < CHUNKS_; ++ch) {
        const int n0 = (nsplit * CHUNKS_ + ch) * 64;

        float qacc[4][4] = {};
        float kacc[4][4] = {};

        for (int kc = 0; kc < C_; kc += 64) {
            #pragma unroll
            for (int r = 0; r < 16; ++r) {
                int idx = r * 256 + tid;
                int ic = idx >> 6, cc = idx & 63;
                Wqt[cc][ic] = Wq[ic * C_ + kc + cc];
                Wkt[cc][ic] = Wk[ic * C_ + kc + cc];
            }
            #pragma unroll
            for (int r = 0; r < 16; ++r) {
                int idx = r * 256 + tid;
                int cc = idx >> 6, nn = idx & 63;
                Xt[cc][nn] = x[((size_t)(b * C_ + kc + cc)) * N_ + n0 + nn];
            }
            __syncthreads();
            #pragma unroll
            for (int cc = 0; cc < 64; ++cc) {
                float4 xv = *(const float4*)&Xt[cc][tx * 4];
                float4 wq = *(const float4*)&Wqt[cc][ty * 4];
                float4 wk = *(const float4*)&Wkt[cc][ty * 4];
                FMA16(qacc, wq, xv);
                FMA16(kacc, wk, xv);
            }
            __syncthreads();
        }

        // Transpose Q,K tiles through LDS (reuse staging buffers):
        // Qlds[nn][i] = Q[i][nn] + bq[i]
        #pragma unroll
        for (int ii = 0; ii < 4; ++ii) {
            float bqv = bq[ty * 4 + ii];
            float bkv = bk[ty * 4 + ii];
            #pragma unroll
            for (int jj = 0; jj < 4; ++jj) {
                Wqt[tx * 4 + jj][ty * 4 + ii] = qacc[ii][jj] + bqv;
                Wkt[tx * 4 + jj][ty * 4 + ii] = kacc[ii][jj] + bkv;
            }
        }
        __syncthreads();

        #pragma unroll
        for (int nn = 0; nn < 64; ++nn) {
            float4 qv = *(const float4*)&Wqt[nn][ty * 4];  // i-quad
            float4 kv = *(const float4*)&Wkt[nn][tx * 4];  // j-quad
            FMA16(sacc, qv, kv);
        }
        __syncthreads();  // before next chunk restages Wqt/Wkt
    }

    #pragma unroll
    for (int i = 0; i < 4; ++i)
        #pragma unroll
        for (int j = 0; j < 4; ++j)
            atomicAdd(&S[(b * IC_ + ty * 4 + i) * IC_ + tx * 4 + j], sacc[i][j]);
}

// ---------------------------------------------------------------------------
// Kernel 2: softmax over axis=1 (over i, per (b,j) column), in place.
// ---------------------------------------------------------------------------
__global__ void softmax_kernel(float* __restrict__ S)
{
    int t = blockIdx.x * blockDim.x + threadIdx.x;
    if (t >= B_ * IC_) return;
    int b = t >> 6, j = t & 63;
    float m = -1e30f;
    for (int i = 0; i < IC_; ++i)
        m = fmaxf(m, S[(b * IC_ + i) * IC_ + j]);
    float s = 0.f;
    for (int i = 0; i < IC_; ++i)
        s += expf(S[(b * IC_ + i) * IC_ + j] - m);
    float inv = 1.0f / s;
    for (int i = 0; i < IC_; ++i)
        S[(b * IC_ + i) * IC_ + j] = expf(S[(b * IC_ + i) * IC_ + j] - m) * inv;
}

// ---------------------------------------------------------------------------
// Kernel 3: M[b,c,j] = sum_o Wr[c,o] * w[b,o,j]   (per-batch 512x64 matrix)
// ---------------------------------------------------------------------------
__global__ __launch_bounds__(256) void mmix_kernel(
    const float* __restrict__ Wr, const float* __restrict__ S,
    float* __restrict__ M)
{
    const int bid   = blockIdx.x;
    const int ctile = bid % 8;
    const int b     = bid / 8;

    __shared__ float Wrt[64][68]; // [o][c']
    __shared__ float wt[64][68];  // [o][j]

    const int tid = threadIdx.x;
    const int tx  = tid & 15;     // j-quad
    const int ty  = tid >> 4;     // c-quad

    #pragma unroll
    for (int r = 0; r < 16; ++r) {
        int idx = r * 256 + tid;
        int cp = idx >> 6, o = idx & 63;
        Wrt[o][cp] = Wr[(ctile * 64 + cp) * IC_ + o];
    }
    #pragma unroll
    for (int r = 0; r < 16; ++r) {
        int idx = r * 256 + tid;
        int o = idx >> 6, j = idx & 63;
        wt[o][j] = S[(b * IC_ + o) * IC_ + j];
    }
    __syncthreads();

    float acc[4][4] = {};
    #pragma unroll
    for (int o = 0; o < 64; ++o) {
        float4 av = *(const float4*)&Wrt[o][ty * 4];
        float4 bv4 = *(const float4*)&wt[o][tx * 4];
        FMA16(acc, av, bv4);
    }

    #pragma unroll
    for (int i = 0; i < 4; ++i) {
        float4 o4;
        o4.x = acc[i][0]; o4.y = acc[i][1]; o4.z = acc[i][2]; o4.w = acc[i][3];
        *(float4*)&M[((size_t)(b * C_ + ctile * 64 + ty * 4 + i)) * IC_ + tx * 4] = o4;
    }
}

// ---------------------------------------------------------------------------
// Kernel 4: fused V projection + output GEMM + bias + residual.
// Per block: one (b, ntile). Phase 1: V tile [64ic x 64n] = Wv·x + bv,
// computed in registers, parked in LDS. Phase 2: for each of 8 c-tiles,
// out[c,n] = sum_j M[b,c,j]·V[j,n] + br[c] + x[c,n].
// V never touches HBM; the V-tile is computed once and reused 8x.
// ---------------------------------------------------------------------------
__global__ __launch_bounds__(256) void vout_kernel(
    const float* __restrict__ x,
    const float* __restrict__ Wv, const float* __restrict__ bv,
    const float* __restrict__ M,  const float* __restrict__ br,
    float* __restrict__ out)
{
    const int bid   = blockIdx.x;
    const int ntile = bid % (N_ / 64);
    const int b     = bid / (N_ / 64);
    const int n0    = ntile * 64;

    __shared__ float S0[64][68];  // Wv staging [cc][ic]; later Mt [j][c']
    __shared__ float S1[64][68];  // x staging [cc][nn]
    __shared__ float Vt[64][68];  // V tile [j][nn]

    const int tid = threadIdx.x;
    const int tx  = tid & 15;     // n-quad
    const int ty  = tid >> 4;     // ic-quad (later c-quad)

    // ---- Phase 1: V tile ----
    float vacc[4][4] = {};
    for (int kc = 0; kc < C_; kc += 64) {
        #pragma unroll
        for (int r = 0; r < 16; ++r) {
            int idx = r * 256 + tid;
            int ic = idx >> 6, cc = idx & 63;
            S0[cc][ic] = Wv[ic * C_ + kc + cc];
        }
        #pragma unroll
        for (int r = 0; r < 16; ++r) {
            int idx = r * 256 + tid;
            int cc = idx >> 6, nn = idx & 63;
            S1[cc][nn] = x[((size_t)(b * C_ + kc + cc)) * N_ + n0 + nn];
        }
        __syncthreads();
        #pragma unroll
        for (int cc = 0; cc < 64; ++cc) {
            float4 wv = *(const float4*)&S0[cc][ty * 4];
            float4 xv = *(const float4*)&S1[cc][tx * 4];
            FMA16(vacc, wv, xv);
        }
        __syncthreads();
    }
    #pragma unroll
    for (int ii = 0; ii < 4; ++ii) {
        float bvv = bv[ty * 4 + ii];
        #pragma unroll
        for (int jj = 0; jj < 4; ++jj)
            Vt[ty * 4 + ii][tx * 4 + jj] = vacc[ii][jj] + bvv;
    }
    __syncthreads();

    // ---- Phase 2: out tiles over 8 c-tiles ----
    for (int ctile = 0; ctile < 8; ++ctile) {
        #pragma unroll
        for (int r = 0; r < 16; ++r) {
            int idx = r * 256 + tid;
            int cp = idx >> 6, j = idx & 63;
            S0[j][cp] = M[((size_t)(b * C_ + ctile * 64 + cp)) * IC_ + j];
        }
        __syncthreads();

        float oacc[4][4] = {};
        #pragma unroll
        for (int j = 0; j < 64; ++j) {
            float4 mv = *(const float4*)&S0[j][ty * 4];  // c-quad
            float4 vv = *(const float4*)&Vt[j][tx * 4];  // n-quad
            FMA16(oacc, mv, vv);
        }

        #pragma unroll
        for (int ii = 0; ii < 4; ++ii) {
            int c = ctile * 64 + ty * 4 + ii;
            size_t base = ((size_t)(b * C_ + c)) * N_ + n0 + tx * 4;
            float4 xr = *(const float4*)&x[base];
            float bb = br[c];
            float4 o4;
            o4.x = oacc[ii][0] + bb + xr.x;
            o4.y = oacc[ii][1] + bb + xr.y;
            o4.z = oacc[ii][2] + bb + xr.z;
            o4.w = oacc[ii][3] + bb + xr.w;
            *(float4*)&out[base] = o4;
        }
        __syncthreads();  // before next ctile restages S0
    }
}

// ---------------------------------------------------------------------------
extern "C" void kernel_launch(void* const* d_in, const int* in_sizes, int n_in,
                              void* d_out, int out_size, void* d_ws, size_t ws_size,
                              hipStream_t stream)
{
    const float* x  = (const float*)d_in[0];
    const float* Wq = (const float*)d_in[1];
    const float* bq = (const float*)d_in[2];
    const float* Wk = (const float*)d_in[3];
    const float* bk = (const float*)d_in[4];
    const float* Wv = (const float*)d_in[5];
    const float* bv = (const float*)d_in[6];
    const float* Wr = (const float*)d_in[7];
    const float* br = (const float*)d_in[8];
    float* out = (float*)d_out;

    // Workspace: S (scores->weights) 128 KB + M (Wr·w) 1 MB = 1.125 MB total.
    float* S = (float*)d_ws;                       // B*IC*IC
    float* M = S + (size_t)B_ * IC_ * IC_;         // B*C*IC

    hipMemsetAsync(S, 0, (size_t)B_ * IC_ * IC_ * sizeof(float), stream);

    qk_scores_kernel<<<B_ * NSPLIT_, 256, 0, stream>>>(x, Wq, bq, Wk, bk, S);
    softmax_kernel  <<<2,            256, 0, stream>>>(S);
    mmix_kernel     <<<B_ * 8,       256, 0, stream>>>(Wr, S, M);
    vout_kernel     <<<B_ * (N_/64), 256, 0, stream>>>(x, Wv, bv, M, br, out);
}